// Round 14
// baseline (176.550 us; speedup 1.0000x reference)
//
#include <hip/hip_runtime.h>
#include <hip/hip_bf16.h>

typedef __bf16 bf16;
typedef __bf16 bf16x4 __attribute__((ext_vector_type(4)));
typedef __bf16 bf16x8 __attribute__((ext_vector_type(8)));
typedef float f32x4 __attribute__((ext_vector_type(4)));

#define MFMA16(a, b, c) __builtin_amdgcn_mfma_f32_16x16x32_bf16((a), (b), (c), 0, 0, 0)

// async global->LDS, 16B per lane; LDS dest = wave-uniform base + lane*16.
__device__ __forceinline__ void async16(const void* g, void* l) {
  typedef const unsigned int __attribute__((address_space(1))) * GP;
  typedef unsigned int __attribute__((address_space(3))) * LP;
  __builtin_amdgcn_global_load_lds((GP)g, (LP)l, 16, 0, 0);
}

// ---------------------------------------------------------------------------
// prep: z<4 -> transpose+convert weight z (fp32 [1024x1024] -> bf16 Wt[n][k]);
// z==4 -> convert x fp32 -> bf16. grid (16,16,5) x 256 threads.
// ---------------------------------------------------------------------------
__global__ __launch_bounds__(256) void prep(
    const float* __restrict__ w0, const float* __restrict__ w1,
    const float* __restrict__ w2, const float* __restrict__ w3,
    const float* __restrict__ x, bf16* __restrict__ wtOut,
    bf16* __restrict__ xOut) {
  const int t = threadIdx.x;
  if (blockIdx.z == 4) {  // x conversion
    size_t base = ((size_t)(blockIdx.y * 16 + blockIdx.x)) * 16384;
#pragma unroll
    for (int p = 0; p < 16; ++p) {
      size_t i = base + (size_t)(p * 256 + t) * 4;
      f32x4 v = *(const f32x4*)&x[i];
      bf16 o[4];
#pragma unroll
      for (int j = 0; j < 4; ++j) o[j] = (bf16)v[j];
      *(ulong1*)&xOut[i] = *(ulong1*)o;
    }
    return;
  }
  __shared__ __align__(16) float tile[64][68];
  const float* src = (blockIdx.z == 0) ? w0 : (blockIdx.z == 1) ? w1
                   : (blockIdx.z == 2) ? w2 : w3;
  bf16* dst = wtOut + (size_t)blockIdx.z * (1024u * 1024u);
  const int bx = blockIdx.x, by = blockIdx.y;
#pragma unroll
  for (int p = 0; p < 4; ++p) {
    int idx = t + p * 256;
    int r = idx >> 4, c4 = idx & 15;
    *(f32x4*)&tile[r][c4 * 4] =
        *(const f32x4*)&src[(size_t)(by * 64 + r) * 1024 + bx * 64 + c4 * 4];
  }
  __syncthreads();
#pragma unroll
  for (int p = 0; p < 2; ++p) {
    int idx = t + p * 256;
    int rn = idx >> 3, c8 = idx & 7;
    bf16x8 v;
#pragma unroll
    for (int i = 0; i < 8; ++i) v[i] = (bf16)tile[c8 * 8 + i][rn];
    *(bf16x8*)&dst[(size_t)(bx * 64 + rn) * 1024 + by * 64 + c8 * 8] = v;
  }
}

// ---------------------------------------------------------------------------
// GEMM (round-13, unchanged): C = A @ W (Bt[n][k]). 128 x (NI*32) tile, BK=32
// dbuf global_load_lds, one barrier per K-step. XCD-swizzled 1D grid:
// bid = (y&7) + 8*(x + XT*(y>>3)); z in grid.y.
// z==0 scaled by scaleZ0; z==2 with vtOut: fused V^T epilogue.
// ---------------------------------------------------------------------------
template <typename OutT, int NI>
__global__ __launch_bounds__(256, 4) void gemm_bt(
    const bf16* __restrict__ A, const bf16* __restrict__ Bt,
    OutT* __restrict__ C, int btStrideZ, int cStrideZ, float scaleZ0,
    bf16* __restrict__ vtOut) {
  constexpr int XT = 1024 / (NI * 32);
  const int bid = blockIdx.x;
  const int rr = bid & 7, tt = bid >> 3;
  const int xb = tt % XT, yb = (tt / XT) * 8 + rr;
  const int zi = blockIdx.y;

  const int tid = threadIdx.x;
  const int wave = tid >> 6, lane = tid & 63;
  const int quad = lane >> 4, l16 = lane & 15;
  const int wm = wave >> 1, wn = wave & 1;
  const int m0 = yb * 128, n0 = xb * (NI * 32);
  const bf16* Bz = Bt + (size_t)zi * (size_t)btStrideZ;
  OutT* Cz = C + (size_t)zi * (size_t)cStrideZ;
  const float sc = (zi == 0) ? scaleZ0 : 1.0f;

  __shared__ __align__(16) bf16 lsA[2][128 * 32];
  __shared__ __align__(16) bf16 lsB[2][NI * 32 * 32];

  const int lrow = lane >> 2;
  const int cgX = (lane & 3) ^ ((lrow >> 1) & 3);
  const int fR = (l16 >> 1) & 3;

  f32x4 acc[4][NI];
#pragma unroll
  for (int i = 0; i < 4; ++i)
#pragma unroll
    for (int j = 0; j < NI; ++j) acc[i][j] = (f32x4){0.f, 0.f, 0.f, 0.f};

#pragma unroll
  for (int c = 0; c < 2; ++c) {
    int chunk = wave * 2 + c;
    int row = chunk * 16 + lrow;
    async16(&A[(size_t)(m0 + row) * 1024 + cgX * 8], &lsA[0][chunk * 512]);
  }
#pragma unroll
  for (int c = 0; c < NI / 2; ++c) {
    int chunk = wave * (NI / 2) + c;
    int row = chunk * 16 + lrow;
    async16(&Bz[(size_t)(n0 + row) * 1024 + cgX * 8], &lsB[0][chunk * 512]);
  }
  __syncthreads();

  for (int it = 0; it < 32; ++it) {
    const int cur = it & 1;
    if (it < 31) {
      int k0n = (it + 1) * 32;
#pragma unroll
      for (int c = 0; c < 2; ++c) {
        int chunk = wave * 2 + c;
        int row = chunk * 16 + lrow;
        async16(&A[(size_t)(m0 + row) * 1024 + k0n + cgX * 8],
                &lsA[cur ^ 1][chunk * 512]);
      }
#pragma unroll
      for (int c = 0; c < NI / 2; ++c) {
        int chunk = wave * (NI / 2) + c;
        int row = chunk * 16 + lrow;
        async16(&Bz[(size_t)(n0 + row) * 1024 + k0n + cgX * 8],
                &lsB[cur ^ 1][chunk * 512]);
      }
    }

    bf16x8 af[4], bfr[NI];
#pragma unroll
    for (int i = 0; i < 4; ++i) {
      int ra = wm * 64 + i * 16 + l16;
      af[i] = *(const bf16x8*)&lsA[cur][ra * 32 + ((quad ^ fR) * 8)];
    }
#pragma unroll
    for (int ni = 0; ni < NI; ++ni) {
      int rb = wn * (NI * 16) + ni * 16 + l16;
      bfr[ni] = *(const bf16x8*)&lsB[cur][rb * 32 + ((quad ^ fR) * 8)];
    }
#pragma unroll
    for (int mi = 0; mi < 4; ++mi)
#pragma unroll
      for (int ni = 0; ni < NI; ++ni)
        acc[mi][ni] = MFMA16(af[mi], bfr[ni], acc[mi][ni]);

    __syncthreads();
  }

  if (zi == 2 && vtOut != nullptr) {
#pragma unroll
    for (int mi = 0; mi < 4; ++mi)
#pragma unroll
      for (int ni = 0; ni < NI; ++ni) {
        int col = n0 + wn * (NI * 16) + ni * 16 + l16;
        int h = col >> 6, d = col & 63;
        int row = m0 + wm * 64 + mi * 16 + quad * 4;
        int b = row >> 11, s = row & 2047;
        bf16 o[4];
#pragma unroll
        for (int r = 0; r < 4; ++r) o[r] = (bf16)acc[mi][ni][r];
        *(ulong1*)&vtOut[((size_t)(b * 16 + h) * 64 + d) * 2048 + s] =
            *(ulong1*)o;
      }
  } else {
#pragma unroll
    for (int mi = 0; mi < 4; ++mi)
#pragma unroll
      for (int ni = 0; ni < NI; ++ni) {
        int col = n0 + wn * (NI * 16) + ni * 16 + l16;
#pragma unroll
        for (int r = 0; r < 4; ++r) {
          int row = m0 + wm * 64 + mi * 16 + quad * 4 + r;
          Cz[(size_t)row * 1024 + col] = (OutT)(acc[mi][ni][r] * sc);
        }
      }
  }
}

// ---------------------------------------------------------------------------
// Flash attention v5: register-resident P (round-12 math), 64-row q-tile,
// 256 threads, 4 waves x 16 q-rows. Grid 1024 -> 4-5 blocks/CU co-resident
// (deep pool hides barrier drain + fills tails). Balance decode: co-resident
// set {bid, +256, +512, +768} gets qt = {x, 31-x, x, 31-x} (uniform 68
// tiles per group). LDS 32KB: K/V dbuf; Q staging overlays buf1.
// ---------------------------------------------------------------------------
__global__ __launch_bounds__(256, 4) void attn_fwd(
    const bf16* __restrict__ Q, const bf16* __restrict__ K,
    const bf16* __restrict__ Vt, bf16* __restrict__ O) {
  const int bid = blockIdx.x;
  const int x = bid & 31, y = (bid >> 5) & 7, p = bid >> 8;  // p in 0..3
  const int hb = p * 8 + y;  // 0..31
  const int h = hb & 15, b = hb >> 4;
  const int qt = (p & 1) ? (31 - x) : x;
  const int tid = threadIdx.x;
  const int wave = tid >> 6, lane = tid & 63;
  const int quad = lane >> 4, l16 = lane & 15;

  __shared__ __align__(16) bf16 SMEM[16384];  // 32 KB
  // [0,4096) K0 | [4096,8192) V0 | [8192,12288) K1 | [12288,16384) V1
  // Q staging (64x64 = 4096) overlays K1.
  const int kof[2] = {0, 8192};
  const int vof[2] = {4096, 12288};
  bf16* Qs = &SMEM[8192];

  const size_t base = ((size_t)b * 2048) * 1024 + (size_t)h * 64;
  const bf16* Qb = Q + base;
  const bf16* Kb = K + base;
  const bf16* Vtb = Vt + ((size_t)(b * 16 + h)) * 64 * 2048;
  bf16* Ob = O + base;

  const int lrow = lane >> 3;          // 0..7
  const int cgX = (lane & 7) ^ lrow;   // swizzled col-group

  // stage Q (64x64, pre-scaled by 0.125*log2e in QKV GEMM) + K/V tile 0
#pragma unroll
  for (int c = 0; c < 2; ++c) {
    int chunk = wave * 2 + c;  // 8 chunks x 8 rows
    int row = chunk * 8 + lrow;
    async16(&Qb[(size_t)(qt * 64 + row) * 1024 + cgX * 8], &Qs[chunk * 512]);
    async16(&Kb[(size_t)row * 1024 + cgX * 8],
            &SMEM[kof[0] + chunk * 512]);
    async16(&Vtb[(size_t)row * 2048 + cgX * 8],
            &SMEM[vof[0] + chunk * 512]);
  }
  __syncthreads();

  bf16x8 aq[2];
#pragma unroll
  for (int ks = 0; ks < 2; ++ks) {
    int row = wave * 16 + l16;
    aq[ks] = *(const bf16x8*)&Qs[row * 64 + (((ks * 4 + quad) ^ (l16 & 7)) * 8)];
  }
  __syncthreads();  // Q-frag reads done before buf1 (Q overlay) is written

  const float NEG_INF = -__builtin_inff();
  float ls_acc = 0.f;
  f32x4 Oacc[4];
#pragma unroll
  for (int nt = 0; nt < 4; ++nt) Oacc[nt] = (f32x4){0.f, 0.f, 0.f, 0.f};

  for (int kt = 0; kt <= qt; ++kt) {
    const int cur = kt & 1;
    if (kt < qt) {  // prefetch next K/V tile into alternate buffer
#pragma unroll
      for (int c = 0; c < 2; ++c) {
        int chunk = wave * 2 + c;
        int row = chunk * 8 + lrow;
        async16(&Kb[(size_t)((kt + 1) * 64 + row) * 1024 + cgX * 8],
                &SMEM[kof[cur ^ 1] + chunk * 512]);
        async16(&Vtb[(size_t)row * 2048 + (kt + 1) * 64 + cgX * 8],
                &SMEM[vof[cur ^ 1] + chunk * 512]);
      }
    }

    // S^T = K Q^T : lane -> (key = nt*16+quad*4+r, q = l16)
    f32x4 sv[4];
#pragma unroll
    for (int nt = 0; nt < 4; ++nt) {
      int row = nt * 16 + l16;
      bf16x8 bk0 = *(const bf16x8*)&SMEM[kof[cur] + row * 64 +
                                         ((quad ^ (l16 & 7)) * 8)];
      bf16x8 bk1 = *(const bf16x8*)&SMEM[kof[cur] + row * 64 +
                                         (((4 + quad) ^ (l16 & 7)) * 8)];
      sv[nt] = (f32x4){0.f, 0.f, 0.f, 0.f};
      sv[nt] = MFMA16(bk0, aq[0], sv[nt]);  // A = K-frag, B = Q-frag
      sv[nt] = MFMA16(bk1, aq[1], sv[nt]);
    }

    if (kt == qt) {  // causal mask on the diagonal tile: key_rel > q_rel
      const int q_rel = wave * 16 + l16;
#pragma unroll
      for (int nt = 0; nt < 4; ++nt) {
        const int kb = nt * 16 + quad * 4;
#pragma unroll
        for (int r = 0; r < 4; ++r)
          if (kb + r > q_rel) sv[nt][r] = NEG_INF;
      }
    }

    // exp2 + pack P into A-frags (two 16-key groups per bf16x8)
    bf16x8 apf[2];
#pragma unroll
    for (int a = 0; a < 2; ++a)
#pragma unroll
      for (int g = 0; g < 2; ++g)
#pragma unroll
        for (int r = 0; r < 4; ++r) {
          float pv = exp2f(sv[a * 2 + g][r]);
          ls_acc += pv;
          apf[a][g * 4 + r] = (bf16)pv;
        }

    // PV: D[q][d] += P[q][k] V[k][d], B-frags = two b64 reads from Vs
#pragma unroll
    for (int nt = 0; nt < 4; ++nt) {
      const int R = nt * 16 + l16;
      const int sub = (quad & 1) * 4;
#pragma unroll
      for (int a = 0; a < 2; ++a) {
        const int g0 = a * 4 + (quad >> 1);
        const int g1 = g0 + 2;
        bf16x4 lo = *(const bf16x4*)&SMEM[vof[cur] + R * 64 +
                                          ((g0 ^ (l16 & 7)) * 8) + sub];
        bf16x4 hi = *(const bf16x4*)&SMEM[vof[cur] + R * 64 +
                                          ((g1 ^ (l16 & 7)) * 8) + sub];
        bf16x8 bvf;
#pragma unroll
        for (int i = 0; i < 4; ++i) {
          bvf[i] = lo[i];
          bvf[4 + i] = hi[i];
        }
        Oacc[nt] = MFMA16(apf[a], bvf, Oacc[nt]);
      }
    }

    __syncthreads();  // drains prefetch; publishes buffers
  }

  // epilogue: l(q=l16) = sum over quads; redistribute to q=quad*4+r via shfl
  ls_acc += __shfl_xor(ls_acc, 16, 64);
  ls_acc += __shfl_xor(ls_acc, 32, 64);
  float rl[4];
#pragma unroll
  for (int r = 0; r < 4; ++r) rl[r] = 1.f / __shfl(ls_acc, quad * 4 + r, 64);
#pragma unroll
  for (int nt = 0; nt < 4; ++nt)
#pragma unroll
    for (int r = 0; r < 4; ++r) {
      int row = qt * 64 + wave * 16 + quad * 4 + r;
      Ob[(size_t)row * 1024 + nt * 16 + l16] = (bf16)(Oacc[nt][r] * rl[r]);
    }
}

// ---------------------------------------------------------------------------
// Launch
// ---------------------------------------------------------------------------
extern "C" void kernel_launch(void* const* d_in, const int* in_sizes, int n_in,
                              void* d_out, int out_size, void* d_ws,
                              size_t ws_size, hipStream_t stream) {
  (void)in_sizes; (void)n_in; (void)out_size; (void)ws_size;
  const float* x  = (const float*)d_in[0];
  const float* Wq = (const float*)d_in[1];
  const float* Wk = (const float*)d_in[2];
  const float* Wv = (const float*)d_in[3];
  const float* Wo = (const float*)d_in[4];
  float* out = (float*)d_out;

  bf16* ws = (bf16*)d_ws;
  const size_t WELEM = 1024u * 1024u;
  const size_t TELEM = 4096u * 1024u;
  bf16* wt  = ws;               // 4 transposed weights (8 MB)
  bf16* xbf = ws + 4 * WELEM;   // x bf16 (8 MB)
  bf16* q   = xbf + TELEM;      // q (z=0), k (z=1) via cStrideZ
  bf16* k   = q + TELEM;
  bf16* vt  = k + TELEM;        // V written pre-transposed by QKV epilogue
  bf16* ao  = vt + TELEM;

  const float QSCALE = 0.125f * 1.44269504088896340736f;  // 1/sqrt(64)*log2e

  prep<<<dim3(16, 16, 5), 256, 0, stream>>>(Wq, Wk, Wv, Wo, x, wt, xbf);
  gemm_bt<bf16, 4><<<dim3(256, 3), 256, 0, stream>>>(
      xbf, wt, q, (int)WELEM, (int)TELEM, QSCALE, vt);
  attn_fwd<<<dim3(1024), 256, 0, stream>>>(q, k, vt, ao);
  gemm_bt<float, 2><<<dim3(512, 1), 256, 0, stream>>>(
      ao, wt + 3 * WELEM, out, 0, 0, 1.0f, nullptr);
}

// Round 15
// 171.092 us; speedup vs baseline: 1.0319x; 1.0319x over previous
//
#include <hip/hip_runtime.h>
#include <hip/hip_bf16.h>

typedef __bf16 bf16;
typedef __bf16 bf16x4 __attribute__((ext_vector_type(4)));
typedef __bf16 bf16x8 __attribute__((ext_vector_type(8)));
typedef float f32x4 __attribute__((ext_vector_type(4)));

#define MFMA16(a, b, c) __builtin_amdgcn_mfma_f32_16x16x32_bf16((a), (b), (c), 0, 0, 0)

// async global->LDS, 16B per lane; LDS dest = wave-uniform base + lane*16.
__device__ __forceinline__ void async16(const void* g, void* l) {
  typedef const unsigned int __attribute__((address_space(1))) * GP;
  typedef unsigned int __attribute__((address_space(3))) * LP;
  __builtin_amdgcn_global_load_lds((GP)g, (LP)l, 16, 0, 0);
}

// ---------------------------------------------------------------------------
// prep: z<4 -> transpose+convert weight z (fp32 [1024x1024] -> bf16 Wt[n][k]);
// z==4 -> convert x fp32 -> bf16. grid (16,16,5) x 256 threads.
// ---------------------------------------------------------------------------
__global__ __launch_bounds__(256) void prep(
    const float* __restrict__ w0, const float* __restrict__ w1,
    const float* __restrict__ w2, const float* __restrict__ w3,
    const float* __restrict__ x, bf16* __restrict__ wtOut,
    bf16* __restrict__ xOut) {
  const int t = threadIdx.x;
  if (blockIdx.z == 4) {  // x conversion
    size_t base = ((size_t)(blockIdx.y * 16 + blockIdx.x)) * 16384;
#pragma unroll
    for (int p = 0; p < 16; ++p) {
      size_t i = base + (size_t)(p * 256 + t) * 4;
      f32x4 v = *(const f32x4*)&x[i];
      bf16 o[4];
#pragma unroll
      for (int j = 0; j < 4; ++j) o[j] = (bf16)v[j];
      *(ulong1*)&xOut[i] = *(ulong1*)o;
    }
    return;
  }
  __shared__ __align__(16) float tile[64][68];
  const float* src = (blockIdx.z == 0) ? w0 : (blockIdx.z == 1) ? w1
                   : (blockIdx.z == 2) ? w2 : w3;
  bf16* dst = wtOut + (size_t)blockIdx.z * (1024u * 1024u);
  const int bx = blockIdx.x, by = blockIdx.y;
#pragma unroll
  for (int p = 0; p < 4; ++p) {
    int idx = t + p * 256;
    int r = idx >> 4, c4 = idx & 15;
    *(f32x4*)&tile[r][c4 * 4] =
        *(const f32x4*)&src[(size_t)(by * 64 + r) * 1024 + bx * 64 + c4 * 4];
  }
  __syncthreads();
#pragma unroll
  for (int p = 0; p < 2; ++p) {
    int idx = t + p * 256;
    int rn = idx >> 3, c8 = idx & 7;
    bf16x8 v;
#pragma unroll
    for (int i = 0; i < 8; ++i) v[i] = (bf16)tile[c8 * 8 + i][rn];
    *(bf16x8*)&dst[(size_t)(bx * 64 + rn) * 1024 + by * 64 + c8 * 8] = v;
  }
}

// ---------------------------------------------------------------------------
// GEMM (round-13): C = A @ W (Bt[n][k]). 128 x (NI*32) tile, BK=32 dbuf
// global_load_lds, one barrier per K-step. XCD-swizzled 1D grid:
// bid = (y&7) + 8*(x + XT*(y>>3)); z in grid.y.
// z==0 scaled by scaleZ0; z==2 with vtOut: fused V^T epilogue with the
// PI-PERMUTED key layout: within each 32-key block, key s=16h+4q+r is
// stored at col 8q+4h+r, so attention's PV B-frag is ONE contiguous b128.
// ---------------------------------------------------------------------------
template <typename OutT, int NI>
__global__ __launch_bounds__(256, 4) void gemm_bt(
    const bf16* __restrict__ A, const bf16* __restrict__ Bt,
    OutT* __restrict__ C, int btStrideZ, int cStrideZ, float scaleZ0,
    bf16* __restrict__ vtOut) {
  constexpr int XT = 1024 / (NI * 32);
  const int bid = blockIdx.x;
  const int rr = bid & 7, tt = bid >> 3;
  const int xb = tt % XT, yb = (tt / XT) * 8 + rr;
  const int zi = blockIdx.y;

  const int tid = threadIdx.x;
  const int wave = tid >> 6, lane = tid & 63;
  const int quad = lane >> 4, l16 = lane & 15;
  const int wm = wave >> 1, wn = wave & 1;
  const int m0 = yb * 128, n0 = xb * (NI * 32);
  const bf16* Bz = Bt + (size_t)zi * (size_t)btStrideZ;
  OutT* Cz = C + (size_t)zi * (size_t)cStrideZ;
  const float sc = (zi == 0) ? scaleZ0 : 1.0f;

  __shared__ __align__(16) bf16 lsA[2][128 * 32];
  __shared__ __align__(16) bf16 lsB[2][NI * 32 * 32];

  const int lrow = lane >> 2;
  const int cgX = (lane & 3) ^ ((lrow >> 1) & 3);
  const int fR = (l16 >> 1) & 3;

  f32x4 acc[4][NI];
#pragma unroll
  for (int i = 0; i < 4; ++i)
#pragma unroll
    for (int j = 0; j < NI; ++j) acc[i][j] = (f32x4){0.f, 0.f, 0.f, 0.f};

#pragma unroll
  for (int c = 0; c < 2; ++c) {
    int chunk = wave * 2 + c;
    int row = chunk * 16 + lrow;
    async16(&A[(size_t)(m0 + row) * 1024 + cgX * 8], &lsA[0][chunk * 512]);
  }
#pragma unroll
  for (int c = 0; c < NI / 2; ++c) {
    int chunk = wave * (NI / 2) + c;
    int row = chunk * 16 + lrow;
    async16(&Bz[(size_t)(n0 + row) * 1024 + cgX * 8], &lsB[0][chunk * 512]);
  }
  __syncthreads();

  for (int it = 0; it < 32; ++it) {
    const int cur = it & 1;
    if (it < 31) {
      int k0n = (it + 1) * 32;
#pragma unroll
      for (int c = 0; c < 2; ++c) {
        int chunk = wave * 2 + c;
        int row = chunk * 16 + lrow;
        async16(&A[(size_t)(m0 + row) * 1024 + k0n + cgX * 8],
                &lsA[cur ^ 1][chunk * 512]);
      }
#pragma unroll
      for (int c = 0; c < NI / 2; ++c) {
        int chunk = wave * (NI / 2) + c;
        int row = chunk * 16 + lrow;
        async16(&Bz[(size_t)(n0 + row) * 1024 + k0n + cgX * 8],
                &lsB[cur ^ 1][chunk * 512]);
      }
    }

    bf16x8 af[4], bfr[NI];
#pragma unroll
    for (int i = 0; i < 4; ++i) {
      int ra = wm * 64 + i * 16 + l16;
      af[i] = *(const bf16x8*)&lsA[cur][ra * 32 + ((quad ^ fR) * 8)];
    }
#pragma unroll
    for (int ni = 0; ni < NI; ++ni) {
      int rb = wn * (NI * 16) + ni * 16 + l16;
      bfr[ni] = *(const bf16x8*)&lsB[cur][rb * 32 + ((quad ^ fR) * 8)];
    }
#pragma unroll
    for (int mi = 0; mi < 4; ++mi)
#pragma unroll
      for (int ni = 0; ni < NI; ++ni)
        acc[mi][ni] = MFMA16(af[mi], bfr[ni], acc[mi][ni]);

    __syncthreads();
  }

  if (zi == 2 && vtOut != nullptr) {
    // V: transposed per head -> vt[(b*16+h)][d][sPerm], pi-permuted keys.
    // s = 32B + 16h + 4q (r=0..3 contiguous) -> sPerm = 32B + 8q + 4h + r.
#pragma unroll
    for (int mi = 0; mi < 4; ++mi)
#pragma unroll
      for (int ni = 0; ni < NI; ++ni) {
        int col = n0 + wn * (NI * 16) + ni * 16 + l16;
        int hd = col >> 6, d = col & 63;
        int row = m0 + wm * 64 + mi * 16 + quad * 4;
        int b = row >> 11, s = row & 2047;
        int s32 = s & 31;
        int sp = (s & ~31) + ((s32 & 12) << 1) + ((s32 >> 4) << 2);
        bf16 o[4];
#pragma unroll
        for (int r = 0; r < 4; ++r) o[r] = (bf16)acc[mi][ni][r];
        *(ulong1*)&vtOut[((size_t)(b * 16 + hd) * 64 + d) * 2048 + sp] =
            *(ulong1*)o;
      }
  } else {
#pragma unroll
    for (int mi = 0; mi < 4; ++mi)
#pragma unroll
      for (int ni = 0; ni < NI; ++ni) {
        int col = n0 + wn * (NI * 16) + ni * 16 + l16;
#pragma unroll
        for (int r = 0; r < 4; ++r) {
          int row = m0 + wm * 64 + mi * 16 + quad * 4 + r;
          Cz[(size_t)row * 1024 + col] = (OutT)(acc[mi][ni][r] * sc);
        }
      }
  }
}

// ---------------------------------------------------------------------------
// Flash attention v6: register-resident P, 128-row q-tile, 512 threads,
// 8 waves x 16 q-rows. S^T = K Q^T; exp2 via vectorized tail (f32x4 lsv
// accumulator, packed bf16 convertvector). PV B-frags are single b128 reads
// thanks to the pi-permuted V layout written by the QKV epilogue.
// K/V dbuf global_load_lds, one barrier per tile; LDS 32KB; grid 512.
// ---------------------------------------------------------------------------
__global__ __launch_bounds__(512, 4) void attn_fwd(
    const bf16* __restrict__ Q, const bf16* __restrict__ K,
    const bf16* __restrict__ Vt, bf16* __restrict__ O) {
  const int bid = blockIdx.x;
  const int x = bid & 15, hb = bid >> 4;
  const int h = hb & 15, b = hb >> 4;
  const int qt = b ? (15 - x) : x;
  const int tid = threadIdx.x;
  const int wave = tid >> 6, lane = tid & 63;
  const int quad = lane >> 4, l16 = lane & 15;

  __shared__ __align__(16) bf16 SMEM[16384];  // 32 KB
  const int kof[2] = {0, 8192};
  const int vof[2] = {4096, 12288};
  bf16* Qs = &SMEM[8192];

  const size_t base = ((size_t)b * 2048) * 1024 + (size_t)h * 64;
  const bf16* Qb = Q + base;
  const bf16* Kb = K + base;
  const bf16* Vtb = Vt + ((size_t)(b * 16 + h)) * 64 * 2048;
  bf16* Ob = O + base;

  const int lrow = lane >> 3;
  const int cgX = (lane & 7) ^ lrow;

#pragma unroll
  for (int c = 0; c < 2; ++c) {
    int chunk = wave * 2 + c;
    int row = chunk * 8 + lrow;
    async16(&Qb[(size_t)(qt * 128 + row) * 1024 + cgX * 8], &Qs[chunk * 512]);
  }
  {
    int row = wave * 8 + lrow;
    async16(&Kb[(size_t)row * 1024 + cgX * 8], &SMEM[kof[0] + wave * 512]);
    async16(&Vtb[(size_t)row * 2048 + cgX * 8], &SMEM[vof[0] + wave * 512]);
  }
  __syncthreads();

  bf16x8 aq[2];
#pragma unroll
  for (int ks = 0; ks < 2; ++ks) {
    int row = wave * 16 + l16;
    aq[ks] = *(const bf16x8*)&Qs[row * 64 + (((ks * 4 + quad) ^ (l16 & 7)) * 8)];
  }
  __syncthreads();  // Q-frag reads done before buf1 (Q overlay) is written

  const float NEG_INF = -__builtin_inff();
  f32x4 lsv = (f32x4){0.f, 0.f, 0.f, 0.f};
  f32x4 Oacc[4];
#pragma unroll
  for (int nt = 0; nt < 4; ++nt) Oacc[nt] = (f32x4){0.f, 0.f, 0.f, 0.f};

  const int kt_end = 2 * qt + 1;
  const int ktd = 2 * qt + (wave >> 2);

  for (int kt = 0; kt <= kt_end; ++kt) {
    const int cur = kt & 1;
    if (kt < kt_end) {
      int row = wave * 8 + lrow;
      async16(&Kb[(size_t)((kt + 1) * 64 + row) * 1024 + cgX * 8],
              &SMEM[kof[cur ^ 1] + wave * 512]);
      async16(&Vtb[(size_t)row * 2048 + (kt + 1) * 64 + cgX * 8],
              &SMEM[vof[cur ^ 1] + wave * 512]);
    }

    if (kt <= ktd) {
      // S^T = K Q^T : lane -> (key = nt*16+quad*4+r, q = l16)
      f32x4 sv[4];
#pragma unroll
      for (int nt = 0; nt < 4; ++nt) {
        int row = nt * 16 + l16;
        bf16x8 bk0 = *(const bf16x8*)&SMEM[kof[cur] + row * 64 +
                                           ((quad ^ (l16 & 7)) * 8)];
        bf16x8 bk1 = *(const bf16x8*)&SMEM[kof[cur] + row * 64 +
                                           (((4 + quad) ^ (l16 & 7)) * 8)];
        sv[nt] = (f32x4){0.f, 0.f, 0.f, 0.f};
        sv[nt] = MFMA16(bk0, aq[0], sv[nt]);
        sv[nt] = MFMA16(bk1, aq[1], sv[nt]);
      }

      if (kt == ktd) {  // causal mask: key_rel > q_rel (key space unpermuted)
        const int q_rel = wave * 16 + l16;
        const int cb = (kt - 2 * qt) * 64;
#pragma unroll
        for (int nt = 0; nt < 4; ++nt) {
          const int kb = cb + nt * 16 + quad * 4;
#pragma unroll
          for (int r = 0; r < 4; ++r)
            if (kb + r > q_rel) sv[nt][r] = NEG_INF;
        }
      }

      // exp2 (vector tail: lsv chain depth 4; packed bf16 conversion)
#pragma unroll
      for (int nt = 0; nt < 4; ++nt) {
#pragma unroll
        for (int r = 0; r < 4; ++r) sv[nt][r] = exp2f(sv[nt][r]);
        lsv += sv[nt];
      }
      bf16x8 apf[2];
#pragma unroll
      for (int a = 0; a < 2; ++a) {
        bf16x4 c0 = __builtin_convertvector(sv[2 * a], bf16x4);
        bf16x4 c1 = __builtin_convertvector(sv[2 * a + 1], bf16x4);
#pragma unroll
        for (int i = 0; i < 4; ++i) {
          apf[a][i] = c0[i];
          apf[a][4 + i] = c1[i];
        }
      }

      // PV: B-frag is ONE b128 (pi-permuted V layout), cg = 4a+quad
#pragma unroll
      for (int nt = 0; nt < 4; ++nt) {
        const int R = nt * 16 + l16;
#pragma unroll
        for (int a = 0; a < 2; ++a) {
          bf16x8 bvf = *(const bf16x8*)&SMEM[vof[cur] + R * 64 +
                                             (((a * 4 + quad) ^ (l16 & 7)) *
                                              8)];
          Oacc[nt] = MFMA16(apf[a], bvf, Oacc[nt]);
        }
      }
    }

    __syncthreads();  // drains prefetch; publishes buffers
  }

  // epilogue: per-lane l = horizontal sum; reduce over quads; redistribute
  float ls_acc = lsv[0] + lsv[1] + lsv[2] + lsv[3];
  ls_acc += __shfl_xor(ls_acc, 16, 64);
  ls_acc += __shfl_xor(ls_acc, 32, 64);
  float rl[4];
#pragma unroll
  for (int r = 0; r < 4; ++r) rl[r] = 1.f / __shfl(ls_acc, quad * 4 + r, 64);
#pragma unroll
  for (int nt = 0; nt < 4; ++nt)
#pragma unroll
    for (int r = 0; r < 4; ++r) {
      int row = qt * 128 + wave * 16 + quad * 4 + r;
      Ob[(size_t)row * 1024 + nt * 16 + l16] = (bf16)(Oacc[nt][r] * rl[r]);
    }
}

// ---------------------------------------------------------------------------
// Launch
// ---------------------------------------------------------------------------
extern "C" void kernel_launch(void* const* d_in, const int* in_sizes, int n_in,
                              void* d_out, int out_size, void* d_ws,
                              size_t ws_size, hipStream_t stream) {
  (void)in_sizes; (void)n_in; (void)out_size; (void)ws_size;
  const float* x  = (const float*)d_in[0];
  const float* Wq = (const float*)d_in[1];
  const float* Wk = (const float*)d_in[2];
  const float* Wv = (const float*)d_in[3];
  const float* Wo = (const float*)d_in[4];
  float* out = (float*)d_out;

  bf16* ws = (bf16*)d_ws;
  const size_t WELEM = 1024u * 1024u;
  const size_t TELEM = 4096u * 1024u;
  bf16* wt  = ws;               // 4 transposed weights (8 MB)
  bf16* xbf = ws + 4 * WELEM;   // x bf16 (8 MB)
  bf16* q   = xbf + TELEM;      // q (z=0), k (z=1) via cStrideZ
  bf16* k   = q + TELEM;
  bf16* vt  = k + TELEM;        // V pre-transposed + pi-permuted by QKV
  bf16* ao  = vt + TELEM;

  const float QSCALE = 0.125f * 1.44269504088896340736f;  // 1/sqrt(64)*log2e

  prep<<<dim3(16, 16, 5), 256, 0, stream>>>(Wq, Wk, Wv, Wo, x, wt, xbf);
  gemm_bt<bf16, 4><<<dim3(256, 3), 256, 0, stream>>>(
      xbf, wt, q, (int)WELEM, (int)TELEM, QSCALE, vt);
  attn_fwd<<<dim3(512), 512, 0, stream>>>(q, k, vt, ao);
  gemm_bt<float, 2><<<dim3(512, 1), 256, 0, stream>>>(
      ao, wt + 3 * WELEM, out, 0, 0, 1.0f, nullptr);
}